// Round 16
// baseline (640.371 us; speedup 1.0000x reference)
//
#include <hip/hip_runtime.h>
#include <math.h>

#define A_TOT 8400
#define B_N   2
#define T_N   100
#define C_N   80
#define E_N   32
#define MH_N  64
#define MW_N  64
#define ROW_N 8363          // 4 + 80 + 85 + 4096 + 4098
#define NROWS (B_N*A_TOT)   // 16800
#define EPSF  1e-9f
#define COMP_CAP 1536       // positives per bt bounded by 1189 (grid mask)
#define NEGINF -1e30f
#define GOUT  2048

typedef float vfloat4 __attribute__((ext_vector_type(4)));

__device__ __forceinline__ float2 tmat_eval(
    float gx1, float gy1, float gx2, float gy2,
    float ax,  float ay,
    float px1, float py1, float px2, float py2,
    float cl, float atg, float atp) {
  float ix1 = fmaxf(gx1,px1), iy1 = fmaxf(gy1,py1);
  float ix2 = fminf(gx2,px2), iy2 = fminf(gy2,py2);
  float inter = fmaxf(ix2-ix1,0.f) * fmaxf(iy2-iy1,0.f);
  float wg = gx2-gx1, hg = gy2-gy1, wp = px2-px1, hp = py2-py1;
  float uni = wg*hg + wp*hp - inter + EPSF;
  float iou = inter / uni;
  float cw = fmaxf(gx2,px2) - fminf(gx1,px1);
  float ch = fmaxf(gy2,py2) - fminf(gy1,py1);
  float c2 = cw*cw + ch*ch + EPSF;
  float dx = gx1+gx2-px1-px2, dy = gy1+gy2-py1-py2;
  float rho2 = (dx*dx + dy*dy) * 0.25f;
  float da = atg - atp;
  float v  = 0.4052847345693511f * da * da;     // 4/pi^2
  float alpha = v / (1.f - iou + v + EPSF);
  float ciou = iou - rho2/c2 - alpha*v;
  float iouc = fminf(fmaxf(ciou, 0.f), 1.f);

  float tm = 0.f;
  if (ax > gx1 && ay > gy1 && ax < gx2 && ay < gy2) {   // strict grid mask
    float cp = 1.f / (1.f + expf(-cl));
    float i2 = iouc * iouc;
    tm = i2*i2*i2 * sqrtf(cp);                 // iou^6 * cls^0.5
  }
  return make_float2(tm, iouc);
}

// ---- kernel 1: per bt: full row CIoU -> tmatT [row][t]; kth/maxt/maxiou ---
__global__ __launch_bounds__(512) void k_score(
    const float* __restrict__ cls_logits, const float* __restrict__ pred_boxes,
    const float* __restrict__ target_bbox, const int* __restrict__ target_cls,
    const float* __restrict__ anchors,
    float* __restrict__ tmatT,
    float* __restrict__ kth, float* __restrict__ maxt, float* __restrict__ maxiou) {
  int bt   = blockIdx.x;
  int b    = bt / T_N;
  int t    = bt - b*T_N;
  int tid  = threadIdx.x;
  int lane = tid & 63, wid = tid >> 6;
  __shared__ float comp[COMP_CAP];
  __shared__ float redm[8], redi[8];
  __shared__ float wtop[8][10];
  __shared__ int   cnt;
  if (tid == 0) cnt = 0;
  __syncthreads();

  float4 g  = *(const float4*)(target_bbox + bt*4);
  int    tc = target_cls[bt];
  float atg = atanf((g.z - g.x) / ((g.w - g.y) + EPSF));

  float lm = 0.f, li = 0.f;
  for (int a = tid; a < A_TOT; a += 512) {
    float ax = anchors[a*2+0], ay = anchors[a*2+1];
    float4 pb = *(const float4*)(pred_boxes + ((size_t)(b*A_TOT+a))*4);
    float cl = cls_logits[((size_t)(b*A_TOT+a))*C_N + tc];
    float atp = atanf((pb.z - pb.x) / ((pb.w - pb.y) + EPSF));
    float2 r = tmat_eval(g.x,g.y,g.z,g.w, ax,ay, pb.x,pb.y,pb.z,pb.w,
                         cl, atg, atp);
    tmatT[((size_t)b*A_TOT + a)*T_N + t] = r.x;
    li = fmaxf(li, r.y);
    if (r.x > 0.f) {
      lm = fmaxf(lm, r.x);
      comp[atomicAdd(&cnt, 1)] = r.x;
    }
  }
  #pragma unroll
  for (int off = 32; off; off >>= 1) {
    lm = fmaxf(lm, __shfl_xor(lm, off));
    li = fmaxf(li, __shfl_xor(li, off));
  }
  if (lane == 0) { redm[wid] = lm; redi[wid] = li; }
  __syncthreads();
  if (tid == 0) {
    float m = redm[0], mi = redi[0];
    #pragma unroll
    for (int w = 1; w < 8; w++) { m = fmaxf(m, redm[w]); mi = fmaxf(mi, redi[w]); }
    maxt[bt] = m; maxiou[bt] = mi;
  }
  int count = cnt;   // safe: after __syncthreads

  int base = wid*64 + lane;
  float e0 = (base        < count) ? comp[base]        : NEGINF;
  float e1 = (base + 512  < count) ? comp[base + 512]  : NEGINF;
  float e2 = (base + 1024 < count) ? comp[base + 1024] : NEGINF;
  float mytop = NEGINF;
  #pragma unroll
  for (int k = 0; k < 10; k++) {
    float bv = e0; int bs = 0;
    if (e1 > bv) { bv = e1; bs = 1; }
    if (e2 > bv) { bv = e2; bs = 2; }
    float v = bv; int id = (lane << 2) | bs;
    #pragma unroll
    for (int off = 32; off; off >>= 1) {
      float ov = __shfl_xor(v, off); int oid = __shfl_xor(id, off);
      if (ov > v || (ov == v && oid < id)) { v = ov; id = oid; }
    }
    if ((id >> 2) == lane) {
      int s = id & 3;
      if (s == 0) e0 = NEGINF; else if (s == 1) e1 = NEGINF; else e2 = NEGINF;
    }
    if (lane == k) mytop = v;
  }
  if (lane < 10) wtop[wid][lane] = mytop;
  __syncthreads();

  if (wid == 0) {
    int ia = lane, ib = 64 + lane;
    float f0 = wtop[ia/10][ia%10];
    float f1 = (ib < 80) ? wtop[ib/10][ib%10] : NEGINF;
    float cur = NEGINF;
    #pragma unroll
    for (int k = 0; k < 10; k++) {
      float bv = f0; int bs = 0;
      if (f1 > bv) { bv = f1; bs = 1; }
      float v = bv; int id = (lane << 1) | bs;
      #pragma unroll
      for (int off = 32; off; off >>= 1) {
        float ov = __shfl_xor(v, off); int oid = __shfl_xor(id, off);
        if (ov > v || (ov == v && oid < id)) { v = ov; id = oid; }
      }
      if ((id >> 1) == lane) { if ((id & 1) == 0) f0 = NEGINF; else f1 = NEGINF; }
      cur = v;
    }
    if (lane == 0) kth[bt] = fmaxf(cur, 0.f);   // <10 positives -> 0 (ref zero-pad)
  }
}

// ---- kernel 2: grid-stride rows: assign (coalesced tmatT) + sparse write --
// (idempotent: launched 10x this round for direct timing attribution)
__global__ __launch_bounds__(256) void k_out(
    const float* __restrict__ cls_logits, const float* __restrict__ pred_boxes,
    const float* __restrict__ mask_embs,  const float* __restrict__ protos,
    const float* __restrict__ t_masks,    const float* __restrict__ tmatT,
    const float* __restrict__ kth, const float* __restrict__ maxt,
    const float* __restrict__ maxiou, const float* __restrict__ target_bbox,
    const int* __restrict__ target_cls, const float* __restrict__ scalers,
    float* __restrict__ out) {
  int tid = threadIdx.x;
  __shared__ float sv[128];
  __shared__ int   st[128];
  __shared__ float semb[E_N];
  __shared__ float ctx[10];

  for (unsigned row = blockIdx.x; row < (unsigned)NROWS; row += GOUT) {
    int b = row >= (unsigned)A_TOT;
    int a = (int)row - b*A_TOT;

    // phase 1: assignment — 100 CONTIGUOUS floats per row (coalesced)
    if (tid < 128) {
      float v = 0.f; int tt = 0x7fff;
      if (tid < T_N) {
        float tv = tmatT[(size_t)row*T_N + tid];
        if (tv > 0.f && tv >= kth[b*T_N + tid]) { v = tv; tt = tid; }
      }
      sv[tid] = v; st[tid] = tt;
    }
    if (tid < E_N) semb[tid] = mask_embs[(size_t)row*E_N + tid];
    __syncthreads();
    if (tid < 64) {
      float v1 = sv[tid];    int t1 = st[tid];
      float v2 = sv[tid+64]; int t2 = st[tid+64];
      if (v2 > v1 || (v2 == v1 && t2 < t1)) { v1 = v2; t1 = t2; }
      #pragma unroll
      for (int off = 32; off; off >>= 1) {
        float ov = __shfl_xor(v1, off); int ot = __shfl_xor(t1, off);
        if (ov > v1 || (ov == v1 && ot < t1)) { v1 = ov; t1 = ot; }
      }
      if (tid == 0) {
        int anyv = v1 > 0.f;
        int u = anyv ? t1 : 0;
        int bu = b*T_N + u;
        float4 tb = *(const float4*)(target_bbox + bu*4);
        float ng = anyv ? v1 / (maxt[bu] + EPSF) * maxiou[bu] : 0.f;
        ctx[0]=tb.x; ctx[1]=tb.y; ctx[2]=tb.z; ctx[3]=tb.w;
        ctx[4]= anyv ? 1.f : 0.f; ctx[5]=ng; ctx[6]=scalers[a];
        ctx[7]= (tb.z-tb.x)*(tb.w-tb.y)/(640.f*640.f);
        ctx[8]=__int_as_float(u); ctx[9]=__int_as_float(target_cls[bu]);
      }
    }
    __syncthreads();
    float tb0=ctx[0], tb1=ctx[1], tb2=ctx[2], tb3=ctx[3];
    float vld=ctx[4], ng=ctx[5], s=ctx[6], area=ctx[7];
    int   u  =__float_as_int(ctx[8]), ct=__float_as_int(ctx[9]);
    bool valid = vld > 0.5f;
    size_t base = (size_t)row * ROW_N;

    // phase 2a: small fields (0..88 contiguous; 89+ct; 4265; 4266)
    if (tid < 92) {
      if (tid < 4)        out[base + tid] = pred_boxes[(size_t)row*4 + tid] / s;
      else if (tid < 84)  out[base + tid] = cls_logits[(size_t)row*C_N + (tid-4)];
      else if (tid < 88) {
        float t = (tid==84)?tb0:((tid==85)?tb1:((tid==86)?tb2:tb3));
        out[base + tid] = t / s;
      }
      else if (tid == 88) out[base + 88] = vld;
      else if (tid == 89) { if (valid) out[base + 89 + ct] = ng; }
      else if (tid == 90) out[base + 4265] = area;
      else                out[base + 4266] = vld;
    }

    if (valid) {
      // phase 2b: in-box rectangle only (exact integer equiv of float compares)
      float x1s=tb0*0.1f, y1s=tb1*0.1f, x2s=tb2*0.1f, y2s=tb3*0.1f;
      int hlo = max(0, (int)ceilf(y1s)), hhi = min(MH_N, (int)ceilf(y2s));
      int wlo = max(0, (int)ceilf(x1s)), whi = min(MW_N, (int)ceilf(x2s));
      int nw = whi - wlo, nh = hhi - hlo;
      int ncell = (nw > 0 && nh > 0) ? nw * nh : 0;
      for (int i = tid; i < ncell; i += 256) {
        int h = hlo + i / nw, w = wlo + i % nw;
        const float* pr = protos + ((size_t)((b*MH_N + h)*MW_N + w)) * E_N;
        float acc = 0.f;
        #pragma unroll
        for (int e = 0; e < E_N; e++) acc += semb[e] * pr[e];
        int p = (h << 6) | w;
        out[base + 169  + p] = 1.f / (1.f + expf(-acc));
        out[base + 4267 + p] = t_masks[((size_t)((b*MH_N + h)*MW_N + w)) * T_N + u];
      }
    }
    __syncthreads();   // protect shared buffers before next row
  }
}

extern "C" void kernel_launch(void* const* d_in, const int* in_sizes, int n_in,
                              void* d_out, int out_size, void* d_ws, size_t ws_size,
                              hipStream_t stream) {
  const float* cls_logits   = (const float*)d_in[0];
  const float* pred_boxes   = (const float*)d_in[1];
  const float* mask_embs    = (const float*)d_in[2];
  const float* protos       = (const float*)d_in[3];
  const int*   target_cls   = (const int*)  d_in[4];
  const float* target_bbox  = (const float*)d_in[5];
  const float* target_masks = (const float*)d_in[6];
  const float* anchors      = (const float*)d_in[7];
  const float* scalers      = (const float*)d_in[8];
  float* out = (float*)d_out;

  // ws layout (floats); ~6.7 MB total
  float* ws     = (float*)d_ws;
  float* tmatT  = ws;                                  // 1,680,000  [row][t]
  float* kth    = tmatT + (size_t)NROWS*T_N;           // 200
  float* maxt   = kth + B_N*T_N;                       // 200
  float* maxiou = maxt + B_N*T_N;                      // 200

  hipMemsetAsync(out, 0, (size_t)out_size * sizeof(float), stream);
  k_score<<<B_N*T_N, 512, 0, stream>>>(cls_logits, pred_boxes, target_bbox,
                                       target_cls, anchors, tmatT, kth, maxt, maxiou);
  // k_out is idempotent; 10x replication for direct timing attribution.
  for (int rep = 0; rep < 10; rep++) {
    k_out<<<GOUT, 256, 0, stream>>>(cls_logits, pred_boxes, mask_embs, protos,
                                    target_masks, tmatT, kth, maxt, maxiou,
                                    target_bbox, target_cls, scalers, out);
  }
}

// Round 17
// 170.236 us; speedup vs baseline: 3.7617x; 3.7617x over previous
//
#include <hip/hip_runtime.h>
#include <math.h>

#define A_TOT 8400
#define B_N   2
#define T_N   100
#define C_N   80
#define E_N   32
#define MH_N  64
#define MW_N  64
#define ROW_N 8363          // 4 + 80 + 85 + 4096 + 4098
#define NROWS (B_N*A_TOT)   // 16800
#define EPSF  1e-9f
#define COMP_CAP 1536       // positives per bt bounded by 1189 (grid mask)
#define NEGINF -1e30f
#define GOUT  2100          // x4 waves = 8400 waves = 2 rows/wave

typedef float vfloat4 __attribute__((ext_vector_type(4)));

__device__ __forceinline__ float2 tmat_eval(
    float gx1, float gy1, float gx2, float gy2,
    float ax,  float ay,
    float px1, float py1, float px2, float py2,
    float cl, float atg, float atp) {
  float ix1 = fmaxf(gx1,px1), iy1 = fmaxf(gy1,py1);
  float ix2 = fminf(gx2,px2), iy2 = fminf(gy2,py2);
  float inter = fmaxf(ix2-ix1,0.f) * fmaxf(iy2-iy1,0.f);
  float wg = gx2-gx1, hg = gy2-gy1, wp = px2-px1, hp = py2-py1;
  float uni = wg*hg + wp*hp - inter + EPSF;
  float iou = inter / uni;
  float cw = fmaxf(gx2,px2) - fminf(gx1,px1);
  float ch = fmaxf(gy2,py2) - fminf(gy1,py1);
  float c2 = cw*cw + ch*ch + EPSF;
  float dx = gx1+gx2-px1-px2, dy = gy1+gy2-py1-py2;
  float rho2 = (dx*dx + dy*dy) * 0.25f;
  float da = atg - atp;
  float v  = 0.4052847345693511f * da * da;     // 4/pi^2
  float alpha = v / (1.f - iou + v + EPSF);
  float ciou = iou - rho2/c2 - alpha*v;
  float iouc = fminf(fmaxf(ciou, 0.f), 1.f);

  float tm = 0.f;
  if (ax > gx1 && ay > gy1 && ax < gx2 && ay < gy2) {   // strict grid mask
    float cp = 1.f / (1.f + expf(-cl));
    float i2 = iouc * iouc;
    tm = i2*i2*i2 * sqrtf(cp);                 // iou^6 * cls^0.5
  }
  return make_float2(tm, iouc);
}

// ---- kernel 1: per bt: full row CIoU -> tmatT [row][t]; kth/maxt/maxiou ---
// (unchanged from round 15/16)
__global__ __launch_bounds__(512) void k_score(
    const float* __restrict__ cls_logits, const float* __restrict__ pred_boxes,
    const float* __restrict__ target_bbox, const int* __restrict__ target_cls,
    const float* __restrict__ anchors,
    float* __restrict__ tmatT,
    float* __restrict__ kth, float* __restrict__ maxt, float* __restrict__ maxiou) {
  int bt   = blockIdx.x;
  int b    = bt / T_N;
  int t    = bt - b*T_N;
  int tid  = threadIdx.x;
  int lane = tid & 63, wid = tid >> 6;
  __shared__ float comp[COMP_CAP];
  __shared__ float redm[8], redi[8];
  __shared__ float wtop[8][10];
  __shared__ int   cnt;
  if (tid == 0) cnt = 0;
  __syncthreads();

  float4 g  = *(const float4*)(target_bbox + bt*4);
  int    tc = target_cls[bt];
  float atg = atanf((g.z - g.x) / ((g.w - g.y) + EPSF));

  float lm = 0.f, li = 0.f;
  for (int a = tid; a < A_TOT; a += 512) {
    float ax = anchors[a*2+0], ay = anchors[a*2+1];
    float4 pb = *(const float4*)(pred_boxes + ((size_t)(b*A_TOT+a))*4);
    float cl = cls_logits[((size_t)(b*A_TOT+a))*C_N + tc];
    float atp = atanf((pb.z - pb.x) / ((pb.w - pb.y) + EPSF));
    float2 r = tmat_eval(g.x,g.y,g.z,g.w, ax,ay, pb.x,pb.y,pb.z,pb.w,
                         cl, atg, atp);
    tmatT[((size_t)b*A_TOT + a)*T_N + t] = r.x;
    li = fmaxf(li, r.y);
    if (r.x > 0.f) {
      lm = fmaxf(lm, r.x);
      comp[atomicAdd(&cnt, 1)] = r.x;
    }
  }
  #pragma unroll
  for (int off = 32; off; off >>= 1) {
    lm = fmaxf(lm, __shfl_xor(lm, off));
    li = fmaxf(li, __shfl_xor(li, off));
  }
  if (lane == 0) { redm[wid] = lm; redi[wid] = li; }
  __syncthreads();
  if (tid == 0) {
    float m = redm[0], mi = redi[0];
    #pragma unroll
    for (int w = 1; w < 8; w++) { m = fmaxf(m, redm[w]); mi = fmaxf(mi, redi[w]); }
    maxt[bt] = m; maxiou[bt] = mi;
  }
  int count = cnt;   // safe: after __syncthreads

  int base = wid*64 + lane;
  float e0 = (base        < count) ? comp[base]        : NEGINF;
  float e1 = (base + 512  < count) ? comp[base + 512]  : NEGINF;
  float e2 = (base + 1024 < count) ? comp[base + 1024] : NEGINF;
  float mytop = NEGINF;
  #pragma unroll
  for (int k = 0; k < 10; k++) {
    float bv = e0; int bs = 0;
    if (e1 > bv) { bv = e1; bs = 1; }
    if (e2 > bv) { bv = e2; bs = 2; }
    float v = bv; int id = (lane << 2) | bs;
    #pragma unroll
    for (int off = 32; off; off >>= 1) {
      float ov = __shfl_xor(v, off); int oid = __shfl_xor(id, off);
      if (ov > v || (ov == v && oid < id)) { v = ov; id = oid; }
    }
    if ((id >> 2) == lane) {
      int s = id & 3;
      if (s == 0) e0 = NEGINF; else if (s == 1) e1 = NEGINF; else e2 = NEGINF;
    }
    if (lane == k) mytop = v;
  }
  if (lane < 10) wtop[wid][lane] = mytop;
  __syncthreads();

  if (wid == 0) {
    int ia = lane, ib = 64 + lane;
    float f0 = wtop[ia/10][ia%10];
    float f1 = (ib < 80) ? wtop[ib/10][ib%10] : NEGINF;
    float cur = NEGINF;
    #pragma unroll
    for (int k = 0; k < 10; k++) {
      float bv = f0; int bs = 0;
      if (f1 > bv) { bv = f1; bs = 1; }
      float v = bv; int id = (lane << 1) | bs;
      #pragma unroll
      for (int off = 32; off; off >>= 1) {
        float ov = __shfl_xor(v, off); int oid = __shfl_xor(id, off);
        if (ov > v || (ov == v && oid < id)) { v = ov; id = oid; }
      }
      if ((id >> 1) == lane) { if ((id & 1) == 0) f0 = NEGINF; else f1 = NEGINF; }
      cur = v;
    }
    if (lane == 0) kth[bt] = fmaxf(cur, 0.f);   // <10 positives -> 0 (ref zero-pad)
  }
}

// ---- kernel 2: WAVE-PER-ROW assign + sparse write. ZERO block barriers. ----
__global__ __launch_bounds__(256) void k_out(
    const float* __restrict__ cls_logits, const float* __restrict__ pred_boxes,
    const float* __restrict__ mask_embs,  const float* __restrict__ protos,
    const float* __restrict__ t_masks,    const float* __restrict__ tmatT,
    const float* __restrict__ kth, const float* __restrict__ maxt,
    const float* __restrict__ maxiou, const float* __restrict__ target_bbox,
    const int* __restrict__ target_cls, const float* __restrict__ scalers,
    float* __restrict__ out) {
  int lane = threadIdx.x & 63;
  int wid  = threadIdx.x >> 6;
  __shared__ float semb_s[4][E_N];              // per-wave slice: no barrier needed
  unsigned wg = blockIdx.x * 4u + (unsigned)wid;

  for (unsigned row = wg; row < (unsigned)NROWS; row += GOUT*4u) {
    int b = row >= (unsigned)A_TOT;
    int a = (int)row - b*A_TOT;

    // ---- assignment: lane l holds candidates t=l and t=l+64 ----
    const float* trow = tmatT + (size_t)row * T_N;
    float v1 = 0.f; int t1 = 0x7fff;
    {
      float va = (lane < T_N) ? trow[lane] : 0.f;
      if (lane < T_N && va > 0.f && va >= kth[b*T_N + lane]) { v1 = va; t1 = lane; }
      int l2 = lane + 64;
      if (l2 < T_N) {
        float vb = trow[l2];
        if (vb > 0.f && vb >= kth[b*T_N + l2]) {
          if (vb > v1) { v1 = vb; t1 = l2; }   // tie keeps smaller t (t1=lane<l2)
        }
      }
    }
    #pragma unroll
    for (int off = 32; off; off >>= 1) {
      float ov = __shfl_xor(v1, off); int ot = __shfl_xor(t1, off);
      if (ov > v1 || (ov == v1 && ot < t1)) { v1 = ov; t1 = ot; }
    }
    // all lanes now hold the winner; compute ctx redundantly
    int  anyv = v1 > 0.f;
    int  u    = anyv ? t1 : 0;
    int  bu   = b*T_N + u;
    float4 tb = *(const float4*)(target_bbox + bu*4);
    float ng  = anyv ? v1 / (maxt[bu] + EPSF) * maxiou[bu] : 0.f;
    float vld = anyv ? 1.f : 0.f;
    float s   = scalers[a];
    float area = (tb.z - tb.x)*(tb.w - tb.y)/(640.f*640.f);
    int  ct   = target_cls[bu];
    bool valid = anyv != 0;
    size_t base = (size_t)row * ROW_N;

    // semb -> per-wave LDS (wave-synchronous, no barrier)
    if (lane < E_N) semb_s[wid][lane] = mask_embs[(size_t)row*E_N + lane];

    // ---- small fields: two lane-steps ----
    {
      unsigned p = (unsigned)lane;               // 0..63
      float val = (p < 4u) ? pred_boxes[(size_t)row*4 + p] / s
                           : cls_logits[(size_t)row*C_N + (p-4u)];
      out[base + p] = val;
    }
    if (lane < 28) {
      unsigned p = 64u + (unsigned)lane;         // 64..91
      if (p < 84u)       out[base + p] = cls_logits[(size_t)row*C_N + (p-4u)];
      else if (p < 88u) {
        float t = (p==84u)?tb.x:((p==85u)?tb.y:((p==86u)?tb.z:tb.w));
        out[base + p] = t / s;
      }
      else if (p == 88u) out[base + 88] = vld;
      else if (p == 89u) { if (valid) out[base + 89 + ct] = ng; }
      else if (p == 90u) out[base + 4265] = area;
      else               out[base + 4266] = vld;
    }

    if (valid) {
      // ---- in-box rectangle only ----
      float x1s=tb.x*0.1f, y1s=tb.y*0.1f, x2s=tb.z*0.1f, y2s=tb.w*0.1f;
      int hlo = max(0, (int)ceilf(y1s)), hhi = min(MH_N, (int)ceilf(y2s));
      int wlo = max(0, (int)ceilf(x1s)), whi = min(MW_N, (int)ceilf(x2s));
      int nw = whi - wlo, nh = hhi - hlo;
      int ncell = (nw > 0 && nh > 0) ? nw * nh : 0;
      for (int i = lane; i < ncell; i += 64) {
        int h = hlo + i / nw, w = wlo + i % nw;
        const float* pr = protos + ((size_t)((b*MH_N + h)*MW_N + w)) * E_N;
        float acc = 0.f;
        #pragma unroll
        for (int e = 0; e < E_N; e++) acc += semb_s[wid][e] * pr[e];
        int p = (h << 6) | w;
        out[base + 169  + p] = 1.f / (1.f + expf(-acc));
        out[base + 4267 + p] = t_masks[((size_t)((b*MH_N + h)*MW_N + w)) * T_N + u];
      }
    }
  }
}

extern "C" void kernel_launch(void* const* d_in, const int* in_sizes, int n_in,
                              void* d_out, int out_size, void* d_ws, size_t ws_size,
                              hipStream_t stream) {
  const float* cls_logits   = (const float*)d_in[0];
  const float* pred_boxes   = (const float*)d_in[1];
  const float* mask_embs    = (const float*)d_in[2];
  const float* protos       = (const float*)d_in[3];
  const int*   target_cls   = (const int*)  d_in[4];
  const float* target_bbox  = (const float*)d_in[5];
  const float* target_masks = (const float*)d_in[6];
  const float* anchors      = (const float*)d_in[7];
  const float* scalers      = (const float*)d_in[8];
  float* out = (float*)d_out;

  // ws layout (floats); ~6.7 MB total
  float* ws     = (float*)d_ws;
  float* tmatT  = ws;                                  // 1,680,000  [row][t]
  float* kth    = tmatT + (size_t)NROWS*T_N;           // 200
  float* maxt   = kth + B_N*T_N;                       // 200
  float* maxiou = maxt + B_N*T_N;                      // 200

  hipMemsetAsync(out, 0, (size_t)out_size * sizeof(float), stream);
  k_score<<<B_N*T_N, 512, 0, stream>>>(cls_logits, pred_boxes, target_bbox,
                                       target_cls, anchors, tmatT, kth, maxt, maxiou);
  k_out<<<GOUT, 256, 0, stream>>>(cls_logits, pred_boxes, mask_embs, protos,
                                  target_masks, tmatT, kth, maxt, maxiou,
                                  target_bbox, target_cls, scalers, out);
}